// Round 11
// baseline (146.088 us; speedup 1.0000x reference)
//
#include <hip/hip_runtime.h>
#include <math.h>

constexpr int K = 512;
constexpr int D = 64;
constexpr int HW = 64 * 64;                      // 4096
constexpr int NPIX = 131072;
constexpr long long NELEM = (long long)NPIX * D; // 8388608
constexpr float BETA = 0.25f;
constexpr int PPB = 128;                         // pixels per block
constexpr int NBLK = NPIX / PPB;                 // 1024 blocks

typedef __attribute__((ext_vector_type(8))) short short8;
typedef __attribute__((ext_vector_type(4))) float f32x4;

union frag_u { uint4 u; short8 s; };

// truncated-bf16 pack: f0 -> low ushort, f1 -> high ushort (one v_perm_b32)
__device__ inline unsigned pk(float f0, float f1) {
    return __builtin_amdgcn_perm(__float_as_uint(f1), __float_as_uint(f0), 0x07060302u);
}

// ---- Prep: build bf16 B-frags (-2*E) + fp32 ||e||^2 into workspace.
// Also zeroes counts + ticket (replaces hipMemsetAsync).
__global__ void vq_prep(const float* __restrict__ E,
                        uint4* __restrict__ gsb, float* __restrict__ eef,
                        unsigned int* __restrict__ counts,
                        unsigned int* __restrict__ ticket) {
    const int n = blockIdx.x * 128 + threadIdx.x;   // 0..511
    counts[n] = 0u;
    if (n == 0) *ticket = 0u;
    const float4* er = (const float4*)(E + (size_t)n * D);
    const int tile = n >> 4, col = n & 15;
    float acc = 0.f;
#pragma unroll
    for (int g = 0; g < 8; ++g) {
        float4 c0 = er[2 * g], c1 = er[2 * g + 1];
        acc = fmaf(c0.x, c0.x, acc); acc = fmaf(c0.y, c0.y, acc);
        acc = fmaf(c0.z, c0.z, acc); acc = fmaf(c0.w, c0.w, acc);
        acc = fmaf(c1.x, c1.x, acc); acc = fmaf(c1.y, c1.y, acc);
        acc = fmaf(c1.z, c1.z, acc); acc = fmaf(c1.w, c1.w, acc);
        uint4 w;
        w.x = pk(-2.f * c0.x, -2.f * c0.y);
        w.y = pk(-2.f * c0.z, -2.f * c0.w);
        w.z = pk(-2.f * c1.x, -2.f * c1.y);
        w.w = pk(-2.f * c1.z, -2.f * c1.w);
        gsb[(tile * 2 + (g >> 2)) * 64 + ((g & 3) * 16 + col)] = w;
    }
    eef[n] = acc;   // exact fp32 ||e||^2 (folded into acc-init, not an MFMA)
}

// ---- Fused kernel: R10-verified dist core (coalesced z stage, 6-slot ring,
// ee acc-init, separate hcnt) + R1/R5-verified in-kernel coalesced epilogue
// (E[code] gather from L2, per-d 256B/wave stores) + R1-verified ticket
// finalize. Removes: bks_g round-trip, scat's E^T staging, one launch.
__global__ __launch_bounds__(512, 8) void vq_one(
    const float* __restrict__ z, const float* __restrict__ E,
    float* __restrict__ out, int out_size,
    const uint4* __restrict__ gsb, const float* __restrict__ eef,
    float* __restrict__ sse_arr, unsigned int* __restrict__ counts,
    unsigned int* __restrict__ ticket) {

    __shared__ __align__(16) unsigned short sb[8192];     // 16 KB: ring slots 0-3
    __shared__ __align__(16) unsigned int zs32[32 * 132]; // 16.9 KB A buf; slots 4,5 after death
    __shared__ __align__(16) float eef_s[K];              // 2 KB fp32 ||e||^2
    __shared__ unsigned int hcnt[K];                      // 2 KB histogram (separate!)
    __shared__ int bks[PPB];
    __shared__ float red[8], red2[8];
    __shared__ int sflag;

    const int tid = threadIdx.x;
    const int wave = tid >> 6;      // 0..7 (wave = A-tile)
    const int lane = tid & 63;
    const int quad = lane >> 4;
    const int lx = lane & 15;

    const int p0 = blockIdx.x * PPB;
    const int b = p0 >> 12;
    const int s0p = p0 & (HW - 1);

    const char* gsb_c = (const char*)gsb;

    hcnt[tid] = 0u;   // before stage barrier; never aliased by DMA targets

    // ---- DMA: eef + ring windows 0-3 into slots 0-3 (drained by stage barrier) ----
    __builtin_amdgcn_global_load_lds(
        (const __attribute__((address_space(1))) void*)(eef + wave * 64 + lane),
        (__attribute__((address_space(3))) void*)((char*)eef_s + wave * 256), 4, 0, 0);
    if (wave < 4) {
#pragma unroll
        for (int wn = 0; wn < 4; ++wn)
            __builtin_amdgcn_global_load_lds(
                (const __attribute__((address_space(1))) void*)
                    (gsb_c + (size_t)(4 * wn + wave) * 1024 + lane * 16),
                (__attribute__((address_space(3))) void*)
                    ((char*)sb + wn * 4096 + wave * 1024), 16, 0, 0);
    }

    // ---- z stage: coalesced float4 reads, pk to bf16 pairs -> zs32[dp][px];
    //      exact fp32 ||z||^2 partial from raw values ----
    const float* zb = z + (size_t)b * (D * HW) + s0p;
    float zsqp = 0.f;
#pragma unroll
    for (int i = 0; i < 2; ++i) {
        int idx = i * 512 + tid;            // 0..1023
        int dp = idx >> 5;                  // d-pair row 0..31
        int c4 = idx & 31;                  // float4 slot in 128-px row
        const float* r0 = zb + (size_t)(2 * dp) * HW + c4 * 4;
        float4 v0 = *(const float4*)r0;
        float4 v1 = *(const float4*)(r0 + HW);
        zsqp = fmaf(v0.x, v0.x, zsqp); zsqp = fmaf(v0.y, v0.y, zsqp);
        zsqp = fmaf(v0.z, v0.z, zsqp); zsqp = fmaf(v0.w, v0.w, zsqp);
        zsqp = fmaf(v1.x, v1.x, zsqp); zsqp = fmaf(v1.y, v1.y, zsqp);
        zsqp = fmaf(v1.z, v1.z, zsqp); zsqp = fmaf(v1.w, v1.w, zsqp);
        uint4 w;
        w.x = pk(v0.x, v1.x); w.y = pk(v0.y, v1.y);
        w.z = pk(v0.z, v1.z); w.w = pk(v0.w, v1.w);
        *(uint4*)&zs32[dp * 132 + c4 * 4] = w;    // 132 stride: 16B-aligned rows
    }

    __syncthreads();   // zs32 + hcnt visible; drains ALL vmem -> eef_s + slots 0-3 ready

    // ---- A-frags: 8 plain LDS u32 reads (zs32 DEAD after this point) ----
    frag_u a[2];
    const int pxi = wave * 16 + lx;
#pragma unroll
    for (int c = 0; c < 2; ++c) {
        const int bdp = c * 16 + quad * 4;
        a[c].u.x = zs32[(bdp + 0) * 132 + pxi];
        a[c].u.y = zs32[(bdp + 1) * 132 + pxi];
        a[c].u.z = zs32[(bdp + 2) * 132 + pxi];
        a[c].u.w = zs32[(bdp + 3) * 132 + pxi];
    }

    float best0[4];
#pragma unroll
    for (int r = 0; r < 4; ++r) best0[r] = __uint_as_float(0x7F800000u);

    // ---- Main loop: 8 rounds x 2 windows; 6-slot ring (slots 4,5 in zs32).
    // Per round: vmcnt(2), barrier, issue wins 2r+4,2r+5 (wrap-addressed;
    // stale slots never read), consume wins 2r,2r+1. (R10-verified)
#pragma unroll 1
    for (int r = 0, s0i = 0, e0i = 4; r < 8; ++r) {
        asm volatile("s_waitcnt vmcnt(2)" ::: "memory");
        __builtin_amdgcn_s_barrier();
        __builtin_amdgcn_sched_barrier(0);

        if (wave < 4) {
            const int wiA = (2 * r + 4) & 15, wiB = (2 * r + 5) & 15;
            unsigned short* dA = (e0i < 4) ? sb + e0i * 2048
                                           : (unsigned short*)zs32 + (e0i - 4) * 2048;
            unsigned short* dB = (e0i + 1 < 4) ? sb + (e0i + 1) * 2048
                                               : (unsigned short*)zs32 + (e0i - 3) * 2048;
            __builtin_amdgcn_global_load_lds(
                (const __attribute__((address_space(1))) void*)
                    (gsb_c + (size_t)wiA * 4096 + wave * 1024 + lane * 16),
                (__attribute__((address_space(3))) void*)((char*)dA + wave * 1024), 16, 0, 0);
            __builtin_amdgcn_global_load_lds(
                (const __attribute__((address_space(1))) void*)
                    (gsb_c + (size_t)wiB * 4096 + wave * 1024 + lane * 16),
                (__attribute__((address_space(3))) void*)((char*)dB + wave * 1024), 16, 0, 0);
        }

#pragma unroll
        for (int h = 0; h < 2; ++h) {
            const int sl = s0i + h;
            const unsigned short* sp = (sl < 4) ? sb + sl * 2048
                                                : (const unsigned short*)zs32 + (sl - 4) * 2048;
            const int w = 2 * r + h;
            frag_u b0, b1, b2, b3;
            b0.u = *(const uint4*)&sp[0 * 512 + lane * 8];
            b1.u = *(const uint4*)&sp[1 * 512 + lane * 8];
            b2.u = *(const uint4*)&sp[2 * 512 + lane * 8];
            b3.u = *(const uint4*)&sp[3 * 512 + lane * 8];
            const int ta = 2 * w, tb = 2 * w + 1;
            const float eea = eef_s[ta * 16 + lx];
            const float eeb = eef_s[tb * 16 + lx];
            f32x4 aa = {eea, eea, eea, eea};   // ee folded into acc-init
            f32x4 ab = {eeb, eeb, eeb, eeb};
            aa = __builtin_amdgcn_mfma_f32_16x16x32_bf16(a[0].s, b0.s, aa, 0, 0, 0);
            aa = __builtin_amdgcn_mfma_f32_16x16x32_bf16(a[1].s, b1.s, aa, 0, 0, 0);
            ab = __builtin_amdgcn_mfma_f32_16x16x32_bf16(a[0].s, b2.s, ab, 0, 0, 0);
            ab = __builtin_amdgcn_mfma_f32_16x16x32_bf16(a[1].s, b3.s, ab, 0, 0, 0);
            unsigned cba = (unsigned)(ta * 16 + lx), cbb = (unsigned)(tb * 16 + lx);
#pragma unroll
            for (int q = 0; q < 4; ++q) {
                float ka = __uint_as_float((__float_as_uint(aa[q]) & 0xFFFFFE00u) | cba);
                float kb = __uint_as_float((__float_as_uint(ab[q]) & 0xFFFFFE00u) | cbb);
                best0[q] = fminf(fminf(best0[q], ka), kb);
            }
        }

        s0i += 2; if (s0i == 6) s0i = 0;
        e0i += 2; if (e0i == 6) e0i = 0;
    }

    // ---- Cross-lane argmin + SSE + code to LDS ----
    float lsse = zsqp;
#pragma unroll
    for (int r = 0; r < 4; ++r) {
        float v = best0[r];
#pragma unroll
        for (int m = 1; m < 16; m <<= 1) v = fminf(v, __shfl_xor(v, m, 64));
        if (lx == 4 * quad + r) {
            unsigned u = __float_as_uint(v);
            int c = (int)(u & 0x1FFu);
            bks[wave * 16 + 4 * quad + r] = c;
            atomicAdd(&hcnt[c], 1u);
            lsse += __uint_as_float(u & 0xFFFFFE00u);
        }
    }
#pragma unroll
    for (int off = 32; off > 0; off >>= 1) lsse += __shfl_down(lsse, off, 64);
    if (lane == 0) red[wave] = lsse;

    __syncthreads();   // bks + hcnt + red visible (drains stray wrap DMAs)
    if (tid == 0) {
        float s = 0.f;
#pragma unroll
        for (int i = 0; i < 8; ++i) s += red[i];
        sse_arr[blockIdx.x] = s;
    }

    // ---- Epilogue: thread -> (pixel = tid&127, d-quarter = tid>>7);
    // E[code] gather from L2 (128 KB resident), per-d coalesced stores ----
    {
        int q = tid & (PPB - 1);
        int dq = tid >> 7;          // 0..3
        int bk = bks[q];
        const float4* Er = (const float4*)(E + (size_t)bk * D + dq * 16);
        float* ob = out + 1 + (size_t)b * (D * HW) + (size_t)dq * 16 * HW + s0p + q;
#pragma unroll
        for (int v4i = 0; v4i < 4; ++v4i) {
            float4 e4 = Er[v4i];
            ob[(size_t)(4 * v4i + 0) * HW] = e4.x;
            ob[(size_t)(4 * v4i + 1) * HW] = e4.y;
            ob[(size_t)(4 * v4i + 2) * HW] = e4.z;
            ob[(size_t)(4 * v4i + 3) * HW] = e4.w;
        }
    }

    // ---- flush histogram ----
    {
        unsigned hc = hcnt[tid];
        if (hc) atomicAdd(&counts[tid], hc);
    }

    // ---- fused finalize: last block computes loss + perplexity (R1-verified) ----
    __syncthreads();
    if (tid == 0) {
        __threadfence();
        unsigned t = atomicAdd(ticket, 1u);
        sflag = (t == (unsigned)(NBLK - 1)) ? 1 : 0;
    }
    __syncthreads();
    if (sflag) {
        float cf = (float)atomicAdd(&counts[tid], 0u);
        float pa = cf / (float)NPIX + 1e-10f;
        float t = pa * logf(pa);
        float s = atomicAdd(&sse_arr[tid], 0.0f) + atomicAdd(&sse_arr[tid + 512], 0.0f);
#pragma unroll
        for (int off = 32; off > 0; off >>= 1) {
            t += __shfl_down(t, off, 64);
            s += __shfl_down(s, off, 64);
        }
        if (lane == 0) { red[wave] = t; red2[wave] = s; }
        __syncthreads();
        if (tid == 0) {
            float tot = 0.f, st = 0.f;
#pragma unroll
            for (int i = 0; i < 8; ++i) { tot += red[i]; st += red2[i]; }
            out[0] = (1.f + BETA) * st / (float)NELEM;
            out[out_size - 1] = expf(-tot);
        }
    }
}

extern "C" void kernel_launch(void* const* d_in, const int* in_sizes, int n_in,
                              void* d_out, int out_size, void* d_ws, size_t ws_size,
                              hipStream_t stream) {
    const float* z = (const float*)d_in[0];
    const float* E = (const float*)d_in[1];
    float* out = (float*)d_out;

    unsigned int* base = (unsigned int*)d_ws;
    unsigned int* ticket = base;                             // [0..3]
    unsigned int* counts = base + 4;                         // 512 uints
    float* sse_arr = (float*)(base + 4 + K);                 // 1024 floats
    uint4* gsb = (uint4*)(base + 1540);                      // 64 KB (byte 6160, 16-B aligned)
    float* eef = (float*)(base + 1540 + 4096 * 4);           // 512 floats

    vq_prep<<<4, 128, 0, stream>>>(E, gsb, eef, counts, ticket);
    vq_one<<<NBLK, 512, 0, stream>>>(z, E, out, out_size, gsb, eef,
                                     sse_arr, counts, ticket);
}

// Round 12
// 111.584 us; speedup vs baseline: 1.3092x; 1.3092x over previous
//
#include <hip/hip_runtime.h>
#include <math.h>

constexpr int K = 512;
constexpr int D = 64;
constexpr int HW = 64 * 64;                      // 4096
constexpr int NPIX = 131072;
constexpr long long NELEM = (long long)NPIX * D; // 8388608
constexpr float BETA = 0.25f;
constexpr int PPB = 256;                         // pixels per block (dist)
constexpr int NBLK = NPIX / PPB;                 // 512 blocks

typedef __attribute__((ext_vector_type(8))) short short8;
typedef __attribute__((ext_vector_type(4))) float f32x4;

union frag_u { uint4 u; short8 s; };

// truncated-bf16 pack: f0 -> low ushort, f1 -> high ushort (one v_perm_b32)
__device__ inline unsigned pk(float f0, float f1) {
    return __builtin_amdgcn_perm(__float_as_uint(f1), __float_as_uint(f0), 0x07060302u);
}

// ---- Prep: build bf16 B-frags (-2*E) + fp32 ||e||^2 into workspace.
// Also zeroes counts (replaces hipMemsetAsync). (R10-verified)
__global__ void vq_prep(const float* __restrict__ E,
                        uint4* __restrict__ gsb, float* __restrict__ eef,
                        unsigned int* __restrict__ counts) {
    const int n = blockIdx.x * 128 + threadIdx.x;   // 0..511
    counts[n] = 0u;
    const float4* er = (const float4*)(E + (size_t)n * D);
    const int tile = n >> 4, col = n & 15;
    float acc = 0.f;
#pragma unroll
    for (int g = 0; g < 8; ++g) {
        float4 c0 = er[2 * g], c1 = er[2 * g + 1];
        acc = fmaf(c0.x, c0.x, acc); acc = fmaf(c0.y, c0.y, acc);
        acc = fmaf(c0.z, c0.z, acc); acc = fmaf(c0.w, c0.w, acc);
        acc = fmaf(c1.x, c1.x, acc); acc = fmaf(c1.y, c1.y, acc);
        acc = fmaf(c1.z, c1.z, acc); acc = fmaf(c1.w, c1.w, acc);
        uint4 w;
        w.x = pk(-2.f * c0.x, -2.f * c0.y);
        w.y = pk(-2.f * c0.z, -2.f * c0.w);
        w.z = pk(-2.f * c1.x, -2.f * c1.y);
        w.w = pk(-2.f * c1.z, -2.f * c1.w);
        gsb[(tile * 2 + (g >> 2)) * 64 + ((g & 3) * 16 + col)] = w;
    }
    eef[n] = acc;   // exact fp32 ||e||^2 (folded into acc-init, not an MFMA)
}

// ---- Phase 1: PPB=256, 2 A-tiles per wave (R1-verified decomposition) on the
// R10-verified 6-slot ring. Each B window feeds 2 row-tiles -> LDS-read volume
// and barriers per pixel HALVED vs R10. (512,4): ~128-reg budget (R11's 28-reg
// starvation fix). LDS ~54 KB -> 2 blocks/CU.
__global__ __launch_bounds__(512, 4) void vq_dist(
    const float* __restrict__ z,
    const uint4* __restrict__ gsb, const float* __restrict__ eef,
    unsigned short* __restrict__ bks_g, float* __restrict__ sse_arr,
    unsigned int* __restrict__ counts) {

    __shared__ __align__(16) unsigned short sb[8192];     // 16 KB: ring slots 0-3
    __shared__ __align__(16) unsigned int zs32[32 * 264]; // 33 KB A buf; slots 4,5 after death
    __shared__ __align__(16) float eef_s[K];              // 2 KB fp32 ||e||^2
    __shared__ unsigned int hcnt[K];                      // 2 KB histogram (separate!)
    __shared__ float red[8];

    const int tid = threadIdx.x;
    const int wave = tid >> 6;      // 0..7 (wave = A-tile pair)
    const int lane = tid & 63;
    const int quad = lane >> 4;
    const int lx = lane & 15;

    const int p0 = blockIdx.x * PPB;
    const int b = p0 >> 12;
    const int s0p = p0 & (HW - 1);

    const char* gsb_c = (const char*)gsb;

    hcnt[tid] = 0u;   // before stage barrier; never aliased by DMA targets

    // ---- DMA: eef + ring windows 0-3 into slots 0-3 (drained by stage barrier) ----
    __builtin_amdgcn_global_load_lds(
        (const __attribute__((address_space(1))) void*)(eef + wave * 64 + lane),
        (__attribute__((address_space(3))) void*)((char*)eef_s + wave * 256), 4, 0, 0);
    if (wave < 4) {
#pragma unroll
        for (int wn = 0; wn < 4; ++wn)
            __builtin_amdgcn_global_load_lds(
                (const __attribute__((address_space(1))) void*)
                    (gsb_c + (size_t)(4 * wn + wave) * 1024 + lane * 16),
                (__attribute__((address_space(3))) void*)
                    ((char*)sb + wn * 4096 + wave * 1024), 16, 0, 0);
    }

    // ---- z stage: coalesced float4 reads, pk to bf16 pairs -> zs32[dp][px];
    //      exact fp32 ||z||^2 partial from raw values ----
    const float* zb = z + (size_t)b * (D * HW) + s0p;
    float zsqp = 0.f;
#pragma unroll
    for (int i = 0; i < 4; ++i) {
        int idx = i * 512 + tid;            // 0..2047
        int dp = idx >> 6;                  // d-pair row 0..31
        int c4 = idx & 63;                  // float4 slot in 256-px row
        const float* r0 = zb + (size_t)(2 * dp) * HW + c4 * 4;
        float4 v0 = *(const float4*)r0;
        float4 v1 = *(const float4*)(r0 + HW);
        zsqp = fmaf(v0.x, v0.x, zsqp); zsqp = fmaf(v0.y, v0.y, zsqp);
        zsqp = fmaf(v0.z, v0.z, zsqp); zsqp = fmaf(v0.w, v0.w, zsqp);
        zsqp = fmaf(v1.x, v1.x, zsqp); zsqp = fmaf(v1.y, v1.y, zsqp);
        zsqp = fmaf(v1.z, v1.z, zsqp); zsqp = fmaf(v1.w, v1.w, zsqp);
        uint4 w;
        w.x = pk(v0.x, v1.x); w.y = pk(v0.y, v1.y);
        w.z = pk(v0.z, v1.z); w.w = pk(v0.w, v1.w);
        *(uint4*)&zs32[dp * 264 + c4 * 4] = w;    // 264 stride: 16B-aligned rows
    }

    __syncthreads();   // zs32 + hcnt visible; drains ALL vmem -> eef_s + slots 0-3 ready

    // ---- A-frags: 2 tiles per wave (px wave*32+lx and +16), zs32 DEAD after ----
    frag_u a0[2], a1[2];
    const int pxi0 = wave * 32 + lx;
#pragma unroll
    for (int c = 0; c < 2; ++c) {
        const int bdp = c * 16 + quad * 4;
        a0[c].u.x = zs32[(bdp + 0) * 264 + pxi0];
        a0[c].u.y = zs32[(bdp + 1) * 264 + pxi0];
        a0[c].u.z = zs32[(bdp + 2) * 264 + pxi0];
        a0[c].u.w = zs32[(bdp + 3) * 264 + pxi0];
        a1[c].u.x = zs32[(bdp + 0) * 264 + pxi0 + 16];
        a1[c].u.y = zs32[(bdp + 1) * 264 + pxi0 + 16];
        a1[c].u.z = zs32[(bdp + 2) * 264 + pxi0 + 16];
        a1[c].u.w = zs32[(bdp + 3) * 264 + pxi0 + 16];
    }

    float best0[4], best1[4];
#pragma unroll
    for (int r = 0; r < 4; ++r) {
        best0[r] = __uint_as_float(0x7F800000u);
        best1[r] = __uint_as_float(0x7F800000u);
    }

    // ---- Main loop: 8 rounds x 2 windows; 6-slot ring (slots 4,5 in zs32).
    // Per round: vmcnt(2), barrier, issue wins 2r+4,2r+5 (wrap-addressed;
    // stale slots never read), consume wins 2r,2r+1. (R10-verified schedule)
#pragma unroll 1
    for (int r = 0, s0i = 0, e0i = 4; r < 8; ++r) {
        asm volatile("s_waitcnt vmcnt(2)" ::: "memory");
        __builtin_amdgcn_s_barrier();
        __builtin_amdgcn_sched_barrier(0);

        if (wave < 4) {
            const int wiA = (2 * r + 4) & 15, wiB = (2 * r + 5) & 15;
            unsigned short* dA = (e0i < 4) ? sb + e0i * 2048
                                           : (unsigned short*)zs32 + (e0i - 4) * 2048;
            unsigned short* dB = (e0i + 1 < 4) ? sb + (e0i + 1) * 2048
                                               : (unsigned short*)zs32 + (e0i - 3) * 2048;
            __builtin_amdgcn_global_load_lds(
                (const __attribute__((address_space(1))) void*)
                    (gsb_c + (size_t)wiA * 4096 + wave * 1024 + lane * 16),
                (__attribute__((address_space(3))) void*)((char*)dA + wave * 1024), 16, 0, 0);
            __builtin_amdgcn_global_load_lds(
                (const __attribute__((address_space(1))) void*)
                    (gsb_c + (size_t)wiB * 4096 + wave * 1024 + lane * 16),
                (__attribute__((address_space(3))) void*)((char*)dB + wave * 1024), 16, 0, 0);
        }

#pragma unroll
        for (int h = 0; h < 2; ++h) {
            const int sl = s0i + h;
            const unsigned short* sp = (sl < 4) ? sb + sl * 2048
                                                : (const unsigned short*)zs32 + (sl - 4) * 2048;
            const int w = 2 * r + h;
            frag_u b0, b1, b2, b3;
            b0.u = *(const uint4*)&sp[0 * 512 + lane * 8];
            b1.u = *(const uint4*)&sp[1 * 512 + lane * 8];
            b2.u = *(const uint4*)&sp[2 * 512 + lane * 8];
            b3.u = *(const uint4*)&sp[3 * 512 + lane * 8];
            const int ta = 2 * w, tb = 2 * w + 1;
            const float eea = eef_s[ta * 16 + lx];
            const float eeb = eef_s[tb * 16 + lx];
            f32x4 aa0 = {eea, eea, eea, eea};   // ee folded into acc-init
            f32x4 aa1 = {eea, eea, eea, eea};
            f32x4 ab0 = {eeb, eeb, eeb, eeb};
            f32x4 ab1 = {eeb, eeb, eeb, eeb};
            aa0 = __builtin_amdgcn_mfma_f32_16x16x32_bf16(a0[0].s, b0.s, aa0, 0, 0, 0);
            aa1 = __builtin_amdgcn_mfma_f32_16x16x32_bf16(a1[0].s, b0.s, aa1, 0, 0, 0);
            aa0 = __builtin_amdgcn_mfma_f32_16x16x32_bf16(a0[1].s, b1.s, aa0, 0, 0, 0);
            aa1 = __builtin_amdgcn_mfma_f32_16x16x32_bf16(a1[1].s, b1.s, aa1, 0, 0, 0);
            ab0 = __builtin_amdgcn_mfma_f32_16x16x32_bf16(a0[0].s, b2.s, ab0, 0, 0, 0);
            ab1 = __builtin_amdgcn_mfma_f32_16x16x32_bf16(a1[0].s, b2.s, ab1, 0, 0, 0);
            ab0 = __builtin_amdgcn_mfma_f32_16x16x32_bf16(a0[1].s, b3.s, ab0, 0, 0, 0);
            ab1 = __builtin_amdgcn_mfma_f32_16x16x32_bf16(a1[1].s, b3.s, ab1, 0, 0, 0);
            unsigned cba = (unsigned)(ta * 16 + lx), cbb = (unsigned)(tb * 16 + lx);
#pragma unroll
            for (int q = 0; q < 4; ++q) {
                float ka0 = __uint_as_float((__float_as_uint(aa0[q]) & 0xFFFFFE00u) | cba);
                float kb0 = __uint_as_float((__float_as_uint(ab0[q]) & 0xFFFFFE00u) | cbb);
                best0[q] = fminf(fminf(best0[q], ka0), kb0);
                float ka1 = __uint_as_float((__float_as_uint(aa1[q]) & 0xFFFFFE00u) | cba);
                float kb1 = __uint_as_float((__float_as_uint(ab1[q]) & 0xFFFFFE00u) | cbb);
                best1[q] = fminf(fminf(best1[q], ka1), kb1);
            }
        }

        s0i += 2; if (s0i == 6) s0i = 0;
        e0i += 2; if (e0i == 6) e0i = 0;
    }

    // ---- Cross-lane argmin + SSE + code emit (R1-verified 2-tile pattern) ----
    float lsse = zsqp;
#pragma unroll
    for (int rt = 0; rt < 2; ++rt) {
#pragma unroll
        for (int r = 0; r < 4; ++r) {
            float v = rt == 0 ? best0[r] : best1[r];
#pragma unroll
            for (int m = 1; m < 16; m <<= 1) v = fminf(v, __shfl_xor(v, m, 64));
            if (lx == 4 * quad + r) {   // one writer per (quad,r): row = 4*quad+r
                unsigned u = __float_as_uint(v);
                int c = (int)(u & 0x1FFu);
                bks_g[p0 + wave * 32 + rt * 16 + 4 * quad + r] = (unsigned short)c;
                atomicAdd(&hcnt[c], 1u);
                lsse += __uint_as_float(u & 0xFFFFFE00u);
            }
        }
    }
#pragma unroll
    for (int off = 32; off > 0; off >>= 1) lsse += __shfl_down(lsse, off, 64);
    if (lane == 0) red[wave] = lsse;

    __syncthreads();   // hcnt atomics + red visible (drains stray wrap DMAs)
    if (tid == 0) {
        float s = 0.f;
#pragma unroll
        for (int i = 0; i < 8; ++i) s += red[i];
        sse_arr[blockIdx.x] = s;
    }
    unsigned hc = hcnt[tid];
    if (hc) atomicAdd(&counts[tid], hc);
}

// ---- Phase 2: E^T + codes staged in LDS -> coalesced z_q writes.
// 1024 blocks; block 0 computes loss + perplexity. (R10-verified, except
// sse_arr now has 512 entries -> i<2 loop)
__global__ __launch_bounds__(256, 4) void vq_scat(
    const float* __restrict__ E, float* __restrict__ out, int out_size,
    const unsigned short* __restrict__ bks_g,
    const float* __restrict__ sse_arr, const unsigned int* __restrict__ counts) {

    __shared__ float ET[16 * 513];                 // 32.8 KB: E^T slice [d][k]
    __shared__ __align__(4) unsigned short bcode[512];
    __shared__ float red[4], red2[4];

    const int tid = threadIdx.x;
    const int wave = tid >> 6;
    const int lane = tid & 63;
    const int bid = blockIdx.x;
    const int b = bid >> 5;              // 0..31
    const int d0 = ((bid >> 3) & 3) * 16;
    const int sr = (bid & 7) * 512;

    if (bid == 0) {   // finalize: loss + perplexity (stream order => dist done)
        float t = 0.f, s = 0.f;
#pragma unroll
        for (int i = 0; i < 2; ++i) {
            float cf = (float)counts[tid + 256 * i];
            float pa = cf / (float)NPIX + 1e-10f;
            t += pa * logf(pa);
        }
#pragma unroll
        for (int i = 0; i < 2; ++i) s += sse_arr[tid + 256 * i];   // 512 dist blocks
#pragma unroll
        for (int off = 32; off > 0; off >>= 1) {
            t += __shfl_down(t, off, 64);
            s += __shfl_down(s, off, 64);
        }
        if (lane == 0) { red[wave] = t; red2[wave] = s; }
        __syncthreads();
        if (tid == 0) {
            float tot = 0.f, st = 0.f;
#pragma unroll
            for (int i = 0; i < 4; ++i) { tot += red[i]; st += red2[i]; }
            out[0] = (1.f + BETA) * st / (float)NELEM;
            out[out_size - 1] = expf(-tot);
        }
        __syncthreads();
    }

    // ---- stage E^T (16 d-columns) + this block's 512 codes ----
#pragma unroll
    for (int r2 = 0; r2 < 2; ++r2) {
        int k = tid + r2 * 256;
        const float4* er = (const float4*)(E + (size_t)k * D + d0);
        float4 e0 = er[0], e1 = er[1], e2 = er[2], e3 = er[3];
        ET[ 0 * 513 + k] = e0.x; ET[ 1 * 513 + k] = e0.y;
        ET[ 2 * 513 + k] = e0.z; ET[ 3 * 513 + k] = e0.w;
        ET[ 4 * 513 + k] = e1.x; ET[ 5 * 513 + k] = e1.y;
        ET[ 6 * 513 + k] = e1.z; ET[ 7 * 513 + k] = e1.w;
        ET[ 8 * 513 + k] = e2.x; ET[ 9 * 513 + k] = e2.y;
        ET[10 * 513 + k] = e2.z; ET[11 * 513 + k] = e2.w;
        ET[12 * 513 + k] = e3.x; ET[13 * 513 + k] = e3.y;
        ET[14 * 513 + k] = e3.z; ET[15 * 513 + k] = e3.w;
    }
    {
        unsigned cw = *(const unsigned*)(bks_g + (size_t)b * HW + sr + tid * 2);
        *(unsigned*)&bcode[tid * 2] = cw;
    }
    __syncthreads();

    // ---- coalesced scatter: 32 iters/thread, 256 B per wave-instr ----
    float* ob = out + 1 + (size_t)b * (D * HW) + sr;
#pragma unroll 4
    for (int i = 0; i < 32; ++i) {
        int pid = wave * 32 + i;          // 0..127
        int d = pid >> 3;                 // 0..15
        int ch = pid & 7;                 // 0..7
        int px = ch * 64 + lane;          // 0..511
        int code = (int)bcode[px];
        ob[(size_t)(d0 + d) * HW + px] = ET[d * 513 + code];
    }
}

extern "C" void kernel_launch(void* const* d_in, const int* in_sizes, int n_in,
                              void* d_out, int out_size, void* d_ws, size_t ws_size,
                              hipStream_t stream) {
    const float* z = (const float*)d_in[0];
    const float* E = (const float*)d_in[1];
    float* out = (float*)d_out;

    unsigned int* base = (unsigned int*)d_ws;
    unsigned int* counts = base;                             // 512 uints
    float* sse_arr = (float*)(base + K);                     // 512 floats
    uint4* gsb = (uint4*)(base + 1536);                      // 64 KB (16-B aligned)
    float* eef = (float*)(base + 1536 + 4096 * 4);           // 512 floats
    unsigned short* bks_g = (unsigned short*)(base + 18432); // 256 KB codes

    vq_prep<<<4, 128, 0, stream>>>(E, gsb, eef, counts);
    vq_dist<<<NBLK, 512, 0, stream>>>(z, gsb, eef, bks_g, sse_arr, counts);
    vq_scat<<<1024, 256, 0, stream>>>(E, out, out_size, bks_g, sse_arr, counts);
}